// Round 1
// baseline (405.657 us; speedup 1.0000x reference)
//
#include <hip/hip_runtime.h>
#include <math.h>

// Problem constants (B=8, T=4096, D=256, K=1024)
#define NTOK   32768   // B*T
#define NDIM   256     // D
#define NCODE  1024    // K

// GEMM tiling
#define TM 128
#define TN 128
#define KC 32
#define LDA 132        // padded LDS row stride in floats (132*4B, 16B-aligned, 132%32=4)
#define NTILES (NCODE / TN)   // 8

// ---------------------------------------------------------------------------
// Kernel 0: codebook squared norms. One wave per code.
// ---------------------------------------------------------------------------
__global__ __launch_bounds__(256) void csq_kernel(const float* __restrict__ cb,
                                                  float* __restrict__ csq) {
    int wave = (blockIdx.x * blockDim.x + threadIdx.x) >> 6;  // 0..1023
    int lane = threadIdx.x & 63;
    const float* row = cb + wave * NDIM;
    float s = 0.f;
    #pragma unroll
    for (int d = 0; d < NDIM; d += 64) {
        float v = row[d + lane];
        s += v * v;
    }
    #pragma unroll
    for (int off = 32; off > 0; off >>= 1) s += __shfl_down(s, off, 64);
    if (lane == 0) csq[wave] = s;
}

// ---------------------------------------------------------------------------
// Kernel 1: fused 128x128 fp32 GEMM tile + per-tile argmin partials.
// score = csq[n] - 2 * dot(z[m], cb[n]); per (token, ntile) write best (val, idx).
// ---------------------------------------------------------------------------
__global__ __launch_bounds__(256, 4) void vq_gemm_argmin(
        const float* __restrict__ z, const float* __restrict__ cb,
        const float* __restrict__ csq,
        float* __restrict__ pv, int* __restrict__ pi) {
    __shared__ float As[KC * LDA];   // [k][m], 16.9 KB
    __shared__ float Bs[KC * LDA];   // [k][n], 16.9 KB

    const int tid = threadIdx.x;
    const int tx = tid & 15;         // n-dir thread coord
    const int ty = tid >> 4;         // m-dir thread coord
    const int m0 = blockIdx.x * TM;
    const int n0 = blockIdx.y * TN;

    const float* zA = z  + (size_t)m0 * NDIM;
    const float* cB = cb + (size_t)n0 * NDIM;

    float acc[8][8];
    #pragma unroll
    for (int i = 0; i < 8; ++i)
        #pragma unroll
        for (int j = 0; j < 8; ++j) acc[i][j] = 0.f;

    for (int kc = 0; kc < NDIM; kc += KC) {
        __syncthreads();   // previous iteration's reads done before overwrite
        // Stage 128 rows x 32 dims for A and B: 1024 float4 slots, 4 per thread.
        #pragma unroll
        for (int j = 0; j < 4; ++j) {
            int lin = tid + j * 256;        // 0..1023
            int r = lin >> 3;               // row 0..127
            int q = lin & 7;                // float4 index within 32-dim chunk
            float4 a = *(const float4*)(zA + r * NDIM + kc + q * 4);
            float4 b = *(const float4*)(cB + r * NDIM + kc + q * 4);
            int c0 = q * 4;
            As[(c0 + 0) * LDA + r] = a.x;
            As[(c0 + 1) * LDA + r] = a.y;
            As[(c0 + 2) * LDA + r] = a.z;
            As[(c0 + 3) * LDA + r] = a.w;
            Bs[(c0 + 0) * LDA + r] = b.x;
            Bs[(c0 + 1) * LDA + r] = b.y;
            Bs[(c0 + 2) * LDA + r] = b.z;
            Bs[(c0 + 3) * LDA + r] = b.w;
        }
        __syncthreads();

        #pragma unroll 4
        for (int k = 0; k < KC; ++k) {
            float a[8], b[8];
            *(float4*)&a[0] = *(const float4*)&As[k * LDA + ty * 8];
            *(float4*)&a[4] = *(const float4*)&As[k * LDA + ty * 8 + 4];
            *(float4*)&b[0] = *(const float4*)&Bs[k * LDA + tx * 8];
            *(float4*)&b[4] = *(const float4*)&Bs[k * LDA + tx * 8 + 4];
            #pragma unroll
            for (int mi = 0; mi < 8; ++mi)
                #pragma unroll
                for (int ni = 0; ni < 8; ++ni)
                    acc[mi][ni] = fmaf(a[mi], b[ni], acc[mi][ni]);
        }
    }

    // Per-thread argmin over its 8 codes for each of its 8 tokens.
    float cs[8];
    #pragma unroll
    for (int ni = 0; ni < 8; ++ni) cs[ni] = csq[n0 + tx * 8 + ni];

    __syncthreads();                 // done reading As/Bs; reuse as cand arrays
    float* cv = As;                  // [128][16] candidate vals
    int*   ci = (int*)Bs;            // [128][16] candidate idxs

    #pragma unroll
    for (int mi = 0; mi < 8; ++mi) {
        float bv = INFINITY; int bi = 0;
        #pragma unroll
        for (int ni = 0; ni < 8; ++ni) {
            float d = cs[ni] - 2.0f * acc[mi][ni];
            if (d < bv) { bv = d; bi = ni; }    // strict <: first-min wins
        }
        int m = ty * 8 + mi;
        cv[m * 16 + tx] = bv;
        ci[m * 16 + tx] = n0 + tx * 8 + bi;
    }
    __syncthreads();

    if (tid < TM) {
        float bv = INFINITY; int bi = 0;
        for (int j = 0; j < 16; ++j) {          // tx ascending => idx ascending
            float v = cv[tid * 16 + j];
            if (v < bv) { bv = v; bi = ci[tid * 16 + j]; }
        }
        int token = m0 + tid;
        pv[token * NTILES + blockIdx.y] = bv;
        pi[token * NTILES + blockIdx.y] = bi;
    }
}

// ---------------------------------------------------------------------------
// Kernel 2: reduce 8 partials per token, write index (as float) + gather z_q.
// Block handles 64 tokens with 256 threads.
// ---------------------------------------------------------------------------
__global__ __launch_bounds__(256) void vq_finalize(
        const float* __restrict__ pv, const int* __restrict__ pi,
        const float* __restrict__ cb,
        float* __restrict__ zq, float* __restrict__ io) {
    __shared__ int best[64];
    const int tid = threadIdx.x;
    const int t0 = blockIdx.x * 64;

    if (tid < 64) {
        int token = t0 + tid;
        float bv = INFINITY; int bi = 0;
        #pragma unroll
        for (int j = 0; j < NTILES; ++j) {      // ntile ascending => idx ascending
            float v = pv[token * NTILES + j];
            if (v < bv) { bv = v; bi = pi[token * NTILES + j]; }
        }
        best[tid] = bi;
        io[token] = (float)bi;
    }
    __syncthreads();

    #pragma unroll 4
    for (int j = 0; j < 64; ++j) {
        int bi = best[j];
        zq[(size_t)(t0 + j) * NDIM + tid] = cb[bi * NDIM + tid];
    }
}

// ---------------------------------------------------------------------------
extern "C" void kernel_launch(void* const* d_in, const int* in_sizes, int n_in,
                              void* d_out, int out_size, void* d_ws, size_t ws_size,
                              hipStream_t stream) {
    const float* z  = (const float*)d_in[0];
    const float* cb = (const float*)d_in[1];

    float* zq = (float*)d_out;                        // 32768*256 floats
    float* io = (float*)d_out + (size_t)NTOK * NDIM;  // 32768 floats (indices)

    float* csq = (float*)d_ws;                        // 1024 floats
    float* pv  = csq + NCODE;                         // 32768*8 floats
    int*   pi  = (int*)(pv + (size_t)NTOK * NTILES);  // 32768*8 ints
    // total ws use: (1024 + 2*262144)*4 ≈ 2.1 MB

    csq_kernel<<<NCODE / 4, 256, 0, stream>>>(cb, csq);

    dim3 grid(NTOK / TM, NTILES);                     // 256 x 8
    vq_gemm_argmin<<<grid, 256, 0, stream>>>(z, cb, csq, pv, pi);

    vq_finalize<<<NTOK / 64, 256, 0, stream>>>(pv, pi, cb, zq, io);
}

// Round 2
// 395.610 us; speedup vs baseline: 1.0254x; 1.0254x over previous
//
#include <hip/hip_runtime.h>
#include <math.h>

// Problem constants (B=8, T=4096, D=256, K=1024)
#define NTOK   32768   // B*T
#define NDIM   256     // D
#define NCODE  1024    // K

// GEMM tiling
#define TM 128
#define TN 128
#define KC 32
#define LDA 132        // padded LDS row stride in floats; 132*4=528 bytes, 16B-aligned
#define NTILES (NCODE / TN)   // 8

// XOR swizzle of 8-float column blocks: kills 4-way write conflicts (-> 2-way, free)
// element (k, m) lives at  k*LDA + ((m>>3) ^ ((k>>2)&3))*8 + (m&7)
#define SWZ(k) (((k) >> 2) & 3)

// ---------------------------------------------------------------------------
// Kernel 0: codebook squared norms. One wave per code.
// ---------------------------------------------------------------------------
__global__ __launch_bounds__(256) void csq_kernel(const float* __restrict__ cb,
                                                  float* __restrict__ csq) {
    int wave = (blockIdx.x * blockDim.x + threadIdx.x) >> 6;  // 0..1023
    int lane = threadIdx.x & 63;
    const float* row = cb + wave * NDIM;
    float s = 0.f;
    #pragma unroll
    for (int d = 0; d < NDIM; d += 64) {
        float v = row[d + lane];
        s += v * v;
    }
    #pragma unroll
    for (int off = 32; off > 0; off >>= 1) s += __shfl_down(s, off, 64);
    if (lane == 0) csq[wave] = s;
}

// ---------------------------------------------------------------------------
// Kernel 1: fused 128x128 fp32 GEMM tile + per-tile argmin partials.
// score = csq[n] - 2 * dot(z[m], cb[n]); per (token, ntile) write best (val, idx).
// ---------------------------------------------------------------------------
__global__ __launch_bounds__(256, 3) void vq_gemm_argmin(
        const float* __restrict__ z, const float* __restrict__ cb,
        const float* __restrict__ csq,
        float* __restrict__ pv, int* __restrict__ pi) {
    __shared__ float As[KC * LDA];   // [k][m-swizzled], 16.9 KB
    __shared__ float Bs[KC * LDA];   // [k][n-swizzled], 16.9 KB

    const int tid = threadIdx.x;
    const int tx = tid & 15;         // n-dir thread coord
    const int ty = tid >> 4;         // m-dir thread coord
    const int m0 = blockIdx.x * TM;
    const int n0 = blockIdx.y * TN;

    const float* zA = z  + (size_t)m0 * NDIM;
    const float* cB = cb + (size_t)n0 * NDIM;

    float acc[8][8];
    #pragma unroll
    for (int i = 0; i < 8; ++i)
        #pragma unroll
        for (int j = 0; j < 8; ++j) acc[i][j] = 0.f;

    for (int kc = 0; kc < NDIM; kc += KC) {
        __syncthreads();   // previous iteration's reads done before overwrite
        // Stage 128 rows x 32 dims for A and B: 1024 float4 slots, 4 per thread.
        // Thread handles row r, k-columns c0..c0+3 (transpose into [k][m]).
        #pragma unroll
        for (int j = 0; j < 4; ++j) {
            int lin = tid + j * 256;        // 0..1023
            int r = lin >> 3;               // row 0..127
            int q = lin & 7;                // float4 index within 32-dim chunk
            float4 a = *(const float4*)(zA + r * NDIM + kc + q * 4);
            float4 b = *(const float4*)(cB + r * NDIM + kc + q * 4);
            int rb = r >> 3, ro = r & 7;
            #pragma unroll
            for (int jj = 0; jj < 4; ++jj) {
                int k = q * 4 + jj;
                int addr = k * LDA + ((rb ^ SWZ(k)) * 8 + ro);
                float av = (jj == 0) ? a.x : (jj == 1) ? a.y : (jj == 2) ? a.z : a.w;
                float bv = (jj == 0) ? b.x : (jj == 1) ? b.y : (jj == 2) ? b.z : b.w;
                As[addr] = av;
                Bs[addr] = bv;
            }
        }
        __syncthreads();

        #pragma unroll 4
        for (int k = 0; k < KC; ++k) {
            float a[8], b[8];
            int abase = k * LDA + (ty ^ SWZ(k)) * 8;
            int bbase = k * LDA + (tx ^ SWZ(k)) * 8;
            *(float4*)&a[0] = *(const float4*)&As[abase];
            *(float4*)&a[4] = *(const float4*)&As[abase + 4];
            *(float4*)&b[0] = *(const float4*)&Bs[bbase];
            *(float4*)&b[4] = *(const float4*)&Bs[bbase + 4];
            #pragma unroll
            for (int mi = 0; mi < 8; ++mi)
                #pragma unroll
                for (int ni = 0; ni < 8; ++ni)
                    acc[mi][ni] = fmaf(a[mi], b[ni], acc[mi][ni]);
        }
    }

    // Per-thread argmin over its 8 codes for each of its 8 tokens.
    float cs[8];
    #pragma unroll
    for (int ni = 0; ni < 8; ++ni) cs[ni] = csq[n0 + tx * 8 + ni];

    __syncthreads();                 // done reading As/Bs; reuse as cand arrays
    float* cv = As;                  // [128][16] candidate vals
    int*   ci = (int*)Bs;            // [128][16] candidate idxs

    #pragma unroll
    for (int mi = 0; mi < 8; ++mi) {
        float bv = INFINITY; int bi = 0;
        #pragma unroll
        for (int ni = 0; ni < 8; ++ni) {
            float d = cs[ni] - 2.0f * acc[mi][ni];
            if (d < bv) { bv = d; bi = ni; }    // strict <: first-min wins
        }
        int m = ty * 8 + mi;
        cv[m * 16 + tx] = bv;
        ci[m * 16 + tx] = n0 + tx * 8 + bi;
    }
    __syncthreads();

    if (tid < TM) {
        float bv = INFINITY; int bi = 0;
        for (int j = 0; j < 16; ++j) {          // tx ascending => idx ascending
            float v = cv[tid * 16 + j];
            if (v < bv) { bv = v; bi = ci[tid * 16 + j]; }
        }
        int token = m0 + tid;
        pv[token * NTILES + blockIdx.y] = bv;
        pi[token * NTILES + blockIdx.y] = bi;
    }
}

// ---------------------------------------------------------------------------
// Kernel 2: reduce 8 partials per token, write index (as float) + gather z_q.
// Block handles 64 tokens with 256 threads.
// ---------------------------------------------------------------------------
__global__ __launch_bounds__(256) void vq_finalize(
        const float* __restrict__ pv, const int* __restrict__ pi,
        const float* __restrict__ cb,
        float* __restrict__ zq, float* __restrict__ io) {
    __shared__ int best[64];
    const int tid = threadIdx.x;
    const int t0 = blockIdx.x * 64;

    if (tid < 64) {
        int token = t0 + tid;
        float bv = INFINITY; int bi = 0;
        #pragma unroll
        for (int j = 0; j < NTILES; ++j) {      // ntile ascending => idx ascending
            float v = pv[token * NTILES + j];
            if (v < bv) { bv = v; bi = pi[token * NTILES + j]; }
        }
        best[tid] = bi;
        io[token] = (float)bi;
    }
    __syncthreads();

    #pragma unroll 4
    for (int j = 0; j < 64; ++j) {
        int bi = best[j];
        zq[(size_t)(t0 + j) * NDIM + tid] = cb[bi * NDIM + tid];
    }
}

// ---------------------------------------------------------------------------
extern "C" void kernel_launch(void* const* d_in, const int* in_sizes, int n_in,
                              void* d_out, int out_size, void* d_ws, size_t ws_size,
                              hipStream_t stream) {
    const float* z  = (const float*)d_in[0];
    const float* cb = (const float*)d_in[1];

    float* zq = (float*)d_out;                        // 32768*256 floats
    float* io = (float*)d_out + (size_t)NTOK * NDIM;  // 32768 floats (indices)

    float* csq = (float*)d_ws;                        // 1024 floats
    float* pv  = csq + NCODE;                         // 32768*8 floats
    int*   pi  = (int*)(pv + (size_t)NTOK * NTILES);  // 32768*8 ints
    // total ws use: (1024 + 2*262144)*4 ≈ 2.1 MB

    csq_kernel<<<NCODE / 4, 256, 0, stream>>>(cb, csq);

    dim3 grid(NTOK / TM, NTILES);                     // 256 x 8
    vq_gemm_argmin<<<grid, 256, 0, stream>>>(z, cb, csq, pv, pi);

    vq_finalize<<<NTOK / 64, 256, 0, stream>>>(pv, pi, cb, zq, io);
}

// Round 3
// 166.041 us; speedup vs baseline: 2.4431x; 2.3826x over previous
//
#include <hip/hip_runtime.h>
#include <math.h>

// Problem constants (B=8, T=4096, D=256, K=1024)
#define NTOK   32768
#define NDIM   256
#define NCODE  1024

#define TM 128
#define TN 128
#define KC 32
#define NTILES (NCODE / TN)   // 8

typedef _Float16 f16x8 __attribute__((ext_vector_type(8)));
typedef float    f32x4 __attribute__((ext_vector_type(4)));

// ---------------------------------------------------------------------------
// Kernel 0: codebook squared norms (exact fp32). One wave per code.
// ---------------------------------------------------------------------------
__global__ __launch_bounds__(256) void csq_kernel(const float* __restrict__ cb,
                                                  float* __restrict__ csq) {
    int wave = (blockIdx.x * blockDim.x + threadIdx.x) >> 6;  // 0..1023
    int lane = threadIdx.x & 63;
    const float* row = cb + wave * NDIM;
    float s = 0.f;
    #pragma unroll
    for (int d = 0; d < NDIM; d += 64) {
        float v = row[d + lane];
        s += v * v;
    }
    #pragma unroll
    for (int off = 32; off > 0; off >>= 1) s += __shfl_down(s, off, 64);
    if (lane == 0) csq[wave] = s;
}

// ---------------------------------------------------------------------------
// fp32 -> f16 hi/lo split of 8 consecutive values
// ---------------------------------------------------------------------------
__device__ __forceinline__ void cvt_split8(float4 a0, float4 a1,
                                           f16x8& hi, f16x8& lo) {
    float v[8] = {a0.x, a0.y, a0.z, a0.w, a1.x, a1.y, a1.z, a1.w};
    #pragma unroll
    for (int e = 0; e < 8; ++e) {
        _Float16 h = (_Float16)v[e];
        hi[e] = h;
        lo[e] = (_Float16)(v[e] - (float)h);
    }
}

// ---------------------------------------------------------------------------
// Kernel 1: f16-split MFMA GEMM (cross = z . cb) + fused per-strip argmin.
//   cross ~= ah.bh + al.bh + ah.bl   (error ~1e-5, fp32-grade)
//   score = csq[n] - 2*cross ; partial argmin per (token, n-strip).
// Block: 128x128 tile, 256 threads = 4 waves in 2x2. MFMA 16x16x32 f16.
// Fragment layouts (m89/m91-verified): A[m=lane&15][k=quad*8+j],
// B[n=lane&15][k=quad*8+j], D col=lane&15 row=quad*4+reg.
// ---------------------------------------------------------------------------
__global__ __launch_bounds__(256, 2) void vq_mfma_argmin(
        const float* __restrict__ z, const float* __restrict__ cb,
        const float* __restrict__ csq,
        float* __restrict__ pv, int* __restrict__ pi) {
    __shared__ _Float16 Ah[TM * KC];   // 8 KB each, 32 KB total
    __shared__ _Float16 Al[TM * KC];
    __shared__ _Float16 Bh[TN * KC];
    __shared__ _Float16 Bl[TN * KC];

    const int tid  = threadIdx.x;
    const int nstrip = blockIdx.x;            // 0..7  (fastest: blocks share z-slab)
    const int m0   = blockIdx.y * TM;
    const int n0   = nstrip * TN;
    const int wave = tid >> 6;
    const int lane = tid & 63;
    const int wy = wave >> 1, wx = wave & 1;  // 2x2 wave grid, 64x64 wave tiles
    const int quad = lane >> 4, lr = lane & 15;

    f32x4 acc[4][4];
    #pragma unroll
    for (int i = 0; i < 4; ++i)
        #pragma unroll
        for (int j = 0; j < 4; ++j) acc[i][j] = (f32x4){0.f, 0.f, 0.f, 0.f};

    for (int kc = 0; kc < NDIM; kc += KC) {
        __syncthreads();
        // Stage A (z rows) and B (cb rows): 128 rows x 32 k each, split hi/lo.
        // 512 8-elem chunks per array; 2 chunks per thread per array.
        #pragma unroll
        for (int j = 0; j < 2; ++j) {
            int c  = tid + j * 256;     // 0..511
            int r  = c >> 2;            // row 0..127
            int k8 = c & 3;             // 8-elem group within 32
            const float* pA = z  + (size_t)(m0 + r) * NDIM + kc + k8 * 8;
            const float* pB = cb + (size_t)(n0 + r) * NDIM + kc + k8 * 8;
            float4 a0 = *(const float4*)pA;
            float4 a1 = *(const float4*)(pA + 4);
            float4 b0 = *(const float4*)pB;
            float4 b1 = *(const float4*)(pB + 4);
            f16x8 hi, lo;
            cvt_split8(a0, a1, hi, lo);
            *(f16x8*)&Ah[r * KC + k8 * 8] = hi;
            *(f16x8*)&Al[r * KC + k8 * 8] = lo;
            cvt_split8(b0, b1, hi, lo);
            *(f16x8*)&Bh[r * KC + k8 * 8] = hi;
            *(f16x8*)&Bl[r * KC + k8 * 8] = lo;
        }
        __syncthreads();

        // Load fragments: 4 m-tiles + 4 n-tiles, hi & lo.
        f16x8 fah[4], fal[4], fbh[4], fbl[4];
        #pragma unroll
        for (int t = 0; t < 4; ++t) {
            int aoff = (wy * 64 + t * 16 + lr) * KC + quad * 8;
            int boff = (wx * 64 + t * 16 + lr) * KC + quad * 8;
            fah[t] = *(const f16x8*)&Ah[aoff];
            fal[t] = *(const f16x8*)&Al[aoff];
            fbh[t] = *(const f16x8*)&Bh[boff];
            fbl[t] = *(const f16x8*)&Bl[boff];
        }
        #pragma unroll
        for (int mt = 0; mt < 4; ++mt)
            #pragma unroll
            for (int nt = 0; nt < 4; ++nt) {
                acc[mt][nt] = __builtin_amdgcn_mfma_f32_16x16x32_f16(
                                  fah[mt], fbh[nt], acc[mt][nt], 0, 0, 0);
                acc[mt][nt] = __builtin_amdgcn_mfma_f32_16x16x32_f16(
                                  fal[mt], fbh[nt], acc[mt][nt], 0, 0, 0);
                acc[mt][nt] = __builtin_amdgcn_mfma_f32_16x16x32_f16(
                                  fah[mt], fbl[nt], acc[mt][nt], 0, 0, 0);
            }
    }

    // ---- Epilogue: score + argmin ----
    float cs[4];
    #pragma unroll
    for (int nt = 0; nt < 4; ++nt) cs[nt] = csq[n0 + wx * 64 + nt * 16 + lr];

    __syncthreads();                      // done with tiles; alias for reduce
    float* cv = (float*)Ah;               // [128][2] vals
    int*   ci = (int*)Bh;                 // [128][2] idxs

    #pragma unroll
    for (int mt = 0; mt < 4; ++mt)
        #pragma unroll
        for (int r = 0; r < 4; ++r) {
            float bv = INFINITY; int bi = 0x7fffffff;
            #pragma unroll
            for (int nt = 0; nt < 4; ++nt) {
                float v = cs[nt] - 2.0f * acc[mt][nt][r];
                int   n = n0 + wx * 64 + nt * 16 + lr;
                if (v < bv || (v == bv && n < bi)) { bv = v; bi = n; }
            }
            // butterfly across the 16 lanes sharing this m-row
            #pragma unroll
            for (int msk = 1; msk < 16; msk <<= 1) {
                float ov = __shfl_xor(bv, msk, 64);
                int   oi = __shfl_xor(bi, msk, 64);
                if (ov < bv || (ov == bv && oi < bi)) { bv = ov; bi = oi; }
            }
            if (lr == 0) {
                int ml = wy * 64 + mt * 16 + quad * 4 + r;   // 0..127
                cv[ml * 2 + wx] = bv;
                ci[ml * 2 + wx] = bi;
            }
        }
    __syncthreads();

    if (tid < TM) {
        float v0 = cv[tid * 2], v1 = cv[tid * 2 + 1];
        int   i0 = ci[tid * 2], i1 = ci[tid * 2 + 1];
        bool take1 = (v1 < v0) || (v1 == v0 && i1 < i0);
        int token = m0 + tid;
        pv[token * NTILES + nstrip] = take1 ? v1 : v0;
        pi[token * NTILES + nstrip] = take1 ? i1 : i0;
    }
}

// ---------------------------------------------------------------------------
// Kernel 2: reduce 8 partials per token, write index (as float) + gather z_q.
// ---------------------------------------------------------------------------
__global__ __launch_bounds__(256) void vq_finalize(
        const float* __restrict__ pv, const int* __restrict__ pi,
        const float* __restrict__ cb,
        float* __restrict__ zq, float* __restrict__ io) {
    __shared__ int best[64];
    const int tid = threadIdx.x;
    const int t0 = blockIdx.x * 64;

    if (tid < 64) {
        int token = t0 + tid;
        float bv = INFINITY; int bi = 0x7fffffff;
        #pragma unroll
        for (int j = 0; j < NTILES; ++j) {
            float v = pv[token * NTILES + j];
            int   i = pi[token * NTILES + j];
            if (v < bv || (v == bv && i < bi)) { bv = v; bi = i; }
        }
        best[tid] = bi;
        io[token] = (float)bi;
    }
    __syncthreads();

    #pragma unroll 4
    for (int j = 0; j < 64; ++j) {
        int bi = best[j];
        zq[(size_t)(t0 + j) * NDIM + tid] = cb[bi * NDIM + tid];
    }
}

// ---------------------------------------------------------------------------
extern "C" void kernel_launch(void* const* d_in, const int* in_sizes, int n_in,
                              void* d_out, int out_size, void* d_ws, size_t ws_size,
                              hipStream_t stream) {
    const float* z  = (const float*)d_in[0];
    const float* cb = (const float*)d_in[1];

    float* zq = (float*)d_out;                        // 32768*256 floats
    float* io = (float*)d_out + (size_t)NTOK * NDIM;  // 32768 floats (indices)

    float* csq = (float*)d_ws;                        // 1024 floats
    float* pv  = csq + NCODE;                         // 32768*8 floats
    int*   pi  = (int*)(pv + (size_t)NTOK * NTILES);  // 32768*8 ints
    // ws use ~2.1 MB

    csq_kernel<<<NCODE / 4, 256, 0, stream>>>(cb, csq);

    dim3 grid(NTILES, NTOK / TM);                     // n-strip fastest
    vq_mfma_argmin<<<grid, 256, 0, stream>>>(z, cb, csq, pv, pi);

    vq_finalize<<<NTOK / 64, 256, 0, stream>>>(pv, pi, cb, zq, io);
}

// Round 4
// 163.270 us; speedup vs baseline: 2.4846x; 1.0170x over previous
//
#include <hip/hip_runtime.h>
#include <math.h>

// Problem constants (B=8, T=4096, D=256, K=1024)
#define NTOK   32768
#define NDIM   256
#define NCODE  1024

#define TM 128
#define TN 128
#define KC 32
#define NTILES (NCODE / TN)   // 8

typedef _Float16 f16x8 __attribute__((ext_vector_type(8)));
typedef _Float16 f16x4 __attribute__((ext_vector_type(4)));
typedef float    f32x4 __attribute__((ext_vector_type(4)));

// async global->LDS DMA, 16 B per lane; LDS dst is wave-uniform base + lane*16
__device__ __forceinline__ void gld_lds16(const void* g, void* l) {
    __builtin_amdgcn_global_load_lds(
        (const __attribute__((address_space(1))) void*)g,
        (__attribute__((address_space(3))) void*)l, 16, 0, 0);
}

// ---------------------------------------------------------------------------
// Prep 1: split z (fp32) into f16 hi/lo planes. 8 elems/thread.
// ---------------------------------------------------------------------------
__global__ __launch_bounds__(256) void split_z(const float* __restrict__ z,
                                               _Float16* __restrict__ zh,
                                               _Float16* __restrict__ zl) {
    size_t i = ((size_t)blockIdx.x * 256 + threadIdx.x) * 8;
    float4 a0 = *(const float4*)(z + i);
    float4 a1 = *(const float4*)(z + i + 4);
    float v[8] = {a0.x, a0.y, a0.z, a0.w, a1.x, a1.y, a1.z, a1.w};
    f16x8 hi, lo;
    #pragma unroll
    for (int e = 0; e < 8; ++e) {
        _Float16 h = (_Float16)v[e];
        hi[e] = h;
        lo[e] = (_Float16)(v[e] - (float)h);
    }
    *(f16x8*)&zh[i] = hi;
    *(f16x8*)&zl[i] = lo;
}

// ---------------------------------------------------------------------------
// Prep 2: split codebook into f16 hi/lo + exact fp32 squared norms.
// One wave per code row; lane holds 4 consecutive elems.
// ---------------------------------------------------------------------------
__global__ __launch_bounds__(256) void split_cb(const float* __restrict__ cb,
                                                _Float16* __restrict__ ch,
                                                _Float16* __restrict__ cl,
                                                float* __restrict__ csq) {
    int row  = blockIdx.x * 4 + (threadIdx.x >> 6);   // 0..1023
    int lane = threadIdx.x & 63;
    const float* src = cb + (size_t)row * NDIM + lane * 4;
    float4 v = *(const float4*)src;
    float s = v.x * v.x + v.y * v.y + v.z * v.z + v.w * v.w;
    float a[4] = {v.x, v.y, v.z, v.w};
    f16x4 hi, lo;
    #pragma unroll
    for (int e = 0; e < 4; ++e) {
        _Float16 h = (_Float16)a[e];
        hi[e] = h;
        lo[e] = (_Float16)(a[e] - (float)h);
    }
    *(f16x4*)&ch[(size_t)row * NDIM + lane * 4] = hi;
    *(f16x4*)&cl[(size_t)row * NDIM + lane * 4] = lo;
    #pragma unroll
    for (int off = 32; off > 0; off >>= 1) s += __shfl_down(s, off, 64);
    if (lane == 0) csq[row] = s;
}

// ---------------------------------------------------------------------------
// Kernel G: f16-split MFMA GEMM (cross = z . cb) + fused per-strip argmin.
//   cross ~= ah.bh + al.bh + ah.bl ; score = csq[n] - 2*cross.
// Block: 128x128, 256 threads = 4 waves in 2x2; MFMA 16x16x32 f16.
// Staging: each wave DMAs one plane tile via global_load_lds (zero VALU).
// ---------------------------------------------------------------------------
__global__ __launch_bounds__(256, 3) void vq_mfma_argmin(
        const _Float16* __restrict__ zh, const _Float16* __restrict__ zl,
        const _Float16* __restrict__ ch, const _Float16* __restrict__ cl,
        const float* __restrict__ csq,
        float* __restrict__ pv, int* __restrict__ pi) {
    __shared__ _Float16 Ah[TM * KC];   // 8 KB each, 32 KB total
    __shared__ _Float16 Al[TM * KC];
    __shared__ _Float16 Bh[TN * KC];
    __shared__ _Float16 Bl[TN * KC];

    const int tid    = threadIdx.x;
    const int nstrip = blockIdx.x;            // fastest: blocks share z-slab in L2
    const int m0     = blockIdx.y * TM;
    const int n0     = nstrip * TN;
    const int wave   = tid >> 6;
    const int lane   = tid & 63;
    const int wy = wave >> 1, wx = wave & 1;  // 2x2 wave grid, 64x64 wave tiles
    const int quad = lane >> 4, lr = lane & 15;

    // Each wave stages one plane: 128 rows x 32 k, 8 KB, 8 DMA issues.
    const _Float16* gsrc;
    _Float16* ldst;
    if      (wave == 0) { gsrc = zh + (size_t)m0 * NDIM; ldst = Ah; }
    else if (wave == 1) { gsrc = zl + (size_t)m0 * NDIM; ldst = Al; }
    else if (wave == 2) { gsrc = ch + (size_t)n0 * NDIM; ldst = Bh; }
    else                { gsrc = cl + (size_t)n0 * NDIM; ldst = Bl; }
    gsrc += (lane >> 2) * NDIM + (lane & 3) * 8;   // lane: row=lane/4, k8=lane%4

    f32x4 acc[4][4];
    #pragma unroll
    for (int i = 0; i < 4; ++i)
        #pragma unroll
        for (int j = 0; j < 4; ++j) acc[i][j] = (f32x4){0.f, 0.f, 0.f, 0.f};

    for (int kc = 0; kc < NDIM; kc += KC) {
        __syncthreads();   // prior fragment reads done (also drains nothing else)
        #pragma unroll
        for (int j = 0; j < 8; ++j)   // rows 16j..16j+15
            gld_lds16(gsrc + kc + j * 16 * NDIM, ldst + j * 512);
        __syncthreads();   // drains vmcnt: DMA complete

        f16x8 fah[4], fal[4], fbh[4], fbl[4];
        #pragma unroll
        for (int t = 0; t < 4; ++t) {
            int aoff = (wy * 64 + t * 16 + lr) * KC + quad * 8;
            int boff = (wx * 64 + t * 16 + lr) * KC + quad * 8;
            fah[t] = *(const f16x8*)&Ah[aoff];
            fal[t] = *(const f16x8*)&Al[aoff];
            fbh[t] = *(const f16x8*)&Bh[boff];
            fbl[t] = *(const f16x8*)&Bl[boff];
        }
        #pragma unroll
        for (int mt = 0; mt < 4; ++mt)
            #pragma unroll
            for (int nt = 0; nt < 4; ++nt) {
                acc[mt][nt] = __builtin_amdgcn_mfma_f32_16x16x32_f16(
                                  fah[mt], fbh[nt], acc[mt][nt], 0, 0, 0);
                acc[mt][nt] = __builtin_amdgcn_mfma_f32_16x16x32_f16(
                                  fal[mt], fbh[nt], acc[mt][nt], 0, 0, 0);
                acc[mt][nt] = __builtin_amdgcn_mfma_f32_16x16x32_f16(
                                  fah[mt], fbl[nt], acc[mt][nt], 0, 0, 0);
            }
    }

    // ---- Epilogue: score + argmin (D layout: col=lane&15, row=quad*4+reg) ----
    float cs[4];
    #pragma unroll
    for (int nt = 0; nt < 4; ++nt) cs[nt] = csq[n0 + wx * 64 + nt * 16 + lr];

    __syncthreads();
    float* cv = (float*)Ah;               // [128][2] vals
    int*   ci = (int*)Bh;                 // [128][2] idxs

    #pragma unroll
    for (int mt = 0; mt < 4; ++mt)
        #pragma unroll
        for (int r = 0; r < 4; ++r) {
            float bv = INFINITY; int bi = 0x7fffffff;
            #pragma unroll
            for (int nt = 0; nt < 4; ++nt) {
                float v = cs[nt] - 2.0f * acc[mt][nt][r];
                int   n = n0 + wx * 64 + nt * 16 + lr;
                if (v < bv || (v == bv && n < bi)) { bv = v; bi = n; }
            }
            #pragma unroll
            for (int msk = 1; msk < 16; msk <<= 1) {
                float ov = __shfl_xor(bv, msk, 64);
                int   oi = __shfl_xor(bi, msk, 64);
                if (ov < bv || (ov == bv && oi < bi)) { bv = ov; bi = oi; }
            }
            if (lr == 0) {
                int ml = wy * 64 + mt * 16 + quad * 4 + r;   // 0..127
                cv[ml * 2 + wx] = bv;
                ci[ml * 2 + wx] = bi;
            }
        }
    __syncthreads();

    if (tid < TM) {
        float v0 = cv[tid * 2], v1 = cv[tid * 2 + 1];
        int   i0 = ci[tid * 2], i1 = ci[tid * 2 + 1];
        bool take1 = (v1 < v0) || (v1 == v0 && i1 < i0);
        int token = m0 + tid;
        pv[token * NTILES + nstrip] = take1 ? v1 : v0;
        pi[token * NTILES + nstrip] = take1 ? i1 : i0;
    }
}

// ---------------------------------------------------------------------------
// Finalize: reduce 8 partials/token, write index (as float) + gather z_q.
// 16 tokens per block; 16 threads per row, float4 stores.
// ---------------------------------------------------------------------------
__global__ __launch_bounds__(256) void vq_finalize(
        const float* __restrict__ pv, const int* __restrict__ pi,
        const float* __restrict__ cb,
        float* __restrict__ zq, float* __restrict__ io) {
    __shared__ int best[16];
    const int tid = threadIdx.x;
    const int t0 = blockIdx.x * 16;

    if (tid < 16) {
        int token = t0 + tid;
        float bv = INFINITY; int bi = 0x7fffffff;
        #pragma unroll
        for (int j = 0; j < NTILES; ++j) {
            float v = pv[token * NTILES + j];
            int   i = pi[token * NTILES + j];
            if (v < bv || (v == bv && i < bi)) { bv = v; bi = i; }
        }
        best[tid] = bi;
        io[token] = (float)bi;
    }
    __syncthreads();

    const int tr = tid >> 4, tc = tid & 15;
    const float* src = cb + (size_t)best[tr] * NDIM;
    float*       dst = zq + (size_t)(t0 + tr) * NDIM;
    #pragma unroll
    for (int q = 0; q < 4; ++q) {
        int col = q * 64 + tc * 4;
        *(float4*)&dst[col] = *(const float4*)&src[col];
    }
}

// ---------------------------------------------------------------------------
extern "C" void kernel_launch(void* const* d_in, const int* in_sizes, int n_in,
                              void* d_out, int out_size, void* d_ws, size_t ws_size,
                              hipStream_t stream) {
    const float* z  = (const float*)d_in[0];
    const float* cb = (const float*)d_in[1];

    float* zq = (float*)d_out;                        // 32768*256 floats
    float* io = (float*)d_out + (size_t)NTOK * NDIM;  // 32768 floats (indices)

    // z hi/lo planes live in the zq region (exactly 33.55 MB = zq bytes);
    // the GEMM consumes them before vq_finalize overwrites with final zq.
    _Float16* zh = (_Float16*)d_out;                  // 16.78 MB
    _Float16* zl = zh + (size_t)NTOK * NDIM;          // 16.78 MB

    _Float16* ch  = (_Float16*)d_ws;                  // 0.5 MB
    _Float16* cl  = ch + (size_t)NCODE * NDIM;        // 0.5 MB
    float*    csq = (float*)(cl + (size_t)NCODE * NDIM);  // 4 KB
    float*    pv  = csq + NCODE;                      // 1 MB
    int*      pi  = (int*)(pv + (size_t)NTOK * NTILES);   // 1 MB
    // ws use ~3.1 MB

    split_z<<<NTOK * NDIM / (256 * 8), 256, 0, stream>>>(z, zh, zl);
    split_cb<<<NCODE / 4, 256, 0, stream>>>(cb, ch, cl, csq);

    dim3 grid(NTILES, NTOK / TM);                     // n-strip fastest
    vq_mfma_argmin<<<grid, 256, 0, stream>>>(zh, zl, ch, cl, csq, pv, pi);

    vq_finalize<<<NTOK / 16, 256, 0, stream>>>(pv, pi, cb, zq, io);
}

// Round 5
// 158.123 us; speedup vs baseline: 2.5655x; 1.0325x over previous
//
#include <hip/hip_runtime.h>
#include <math.h>

// Problem constants (B=8, T=4096, D=256, K=1024)
#define NTOK   32768
#define NDIM   256
#define NCODE  1024

#define TM 128
#define TN 128
#define KC 32
#define NTILES (NCODE / TN)   // 8
#define CHUNK  (128 * KC)     // 4096 f16 = 8 KB: one (row-block, kc) plane chunk

typedef _Float16 f16x8 __attribute__((ext_vector_type(8)));
typedef float    f32x4 __attribute__((ext_vector_type(4)));

// async global->LDS DMA, 16 B per lane; LDS dst is wave-uniform base + lane*16
__device__ __forceinline__ void gld_lds16(const void* g, void* l) {
    __builtin_amdgcn_global_load_lds(
        (const __attribute__((address_space(1))) void*)g,
        (__attribute__((address_space(3))) void*)l, 16, 0, 0);
}

// ---------------------------------------------------------------------------
// Prep: split z and cb (fp32) into f16 hi/lo planes in BLOCKED k-major layout:
//   plane[(rowblk*8 + kc8)*4096 + r*32 + k]   (rowblk = row/128, r = row%128)
// so GEMM staging is fully-contiguous 8 KB chunks. Also computes csq exactly.
// Blocks [0,4096): z rows.  Blocks [4096,4224): cb rows (+ csq).
// ---------------------------------------------------------------------------
__global__ __launch_bounds__(256) void prep_split(
        const float* __restrict__ z, const float* __restrict__ cb,
        _Float16* __restrict__ zh, _Float16* __restrict__ zl,
        _Float16* __restrict__ ch, _Float16* __restrict__ cl,
        float* __restrict__ csq) {
    const bool is_cb = blockIdx.x >= 4096;
    const int  bb    = is_cb ? (blockIdx.x - 4096) : blockIdx.x;
    const int  L     = bb * 256 + threadIdx.x;
    const int  row   = L >> 5;          // token or code row
    const int  g     = L & 31;          // 8-dim group within the 256-dim row

    const float* src = (is_cb ? cb : z) + (size_t)row * NDIM + g * 8;
    float4 a0 = *(const float4*)src;
    float4 a1 = *(const float4*)(src + 4);
    float v[8] = {a0.x, a0.y, a0.z, a0.w, a1.x, a1.y, a1.z, a1.w};
    f16x8 hi, lo;
    float s = 0.f;
    #pragma unroll
    for (int e = 0; e < 8; ++e) {
        _Float16 h = (_Float16)v[e];
        hi[e] = h;
        lo[e] = (_Float16)(v[e] - (float)h);
        s += v[e] * v[e];
    }
    const int rb = row >> 7, r = row & 127, kc8 = g >> 2, k8 = g & 3;
    const size_t dst = (size_t)(rb * 8 + kc8) * CHUNK + r * KC + k8 * 8;
    if (is_cb) {
        *(f16x8*)&ch[dst] = hi;
        *(f16x8*)&cl[dst] = lo;
        // row-norm: 32 consecutive lanes cover one row
        #pragma unroll
        for (int off = 16; off > 0; off >>= 1) s += __shfl_down(s, off, 32);
        if ((threadIdx.x & 31) == 0) csq[row] = s;
    } else {
        *(f16x8*)&zh[dst] = hi;
        *(f16x8*)&zl[dst] = lo;
    }
}

// ---------------------------------------------------------------------------
// Kernel G: f16-split MFMA GEMM (cross = z . cb) + fused per-strip argmin.
//   cross ~= ah.bh + al.bh + ah.bl ; score = csq[n] - 2*cross.
// Block: 128x128, 256 threads = 4 waves in 2x2; MFMA 16x16x32 f16.
// Staging: each wave DMAs one plane chunk via 8 contiguous 1 KB gld_lds16.
// ---------------------------------------------------------------------------
__global__ __launch_bounds__(256, 4) void vq_mfma_argmin(
        const _Float16* __restrict__ zh, const _Float16* __restrict__ zl,
        const _Float16* __restrict__ ch, const _Float16* __restrict__ cl,
        const float* __restrict__ csq,
        float2* __restrict__ pq) {
    __shared__ _Float16 Ah[TM * KC];   // 8 KB each, 32 KB total
    __shared__ _Float16 Al[TM * KC];
    __shared__ _Float16 Bh[TN * KC];
    __shared__ _Float16 Bl[TN * KC];

    const int tid    = threadIdx.x;
    const int nstrip = blockIdx.x;            // fastest: blocks share z-slab in L2
    const int mblk   = blockIdx.y;
    const int n0     = nstrip * TN;
    const int wave   = tid >> 6;
    const int lane   = tid & 63;
    const int wy = wave >> 1, wx = wave & 1;  // 2x2 wave grid, 64x64 wave tiles
    const int quad = lane >> 4, lr = lane & 15;

    // Each wave stages one plane: blocked chunk base + lane*16B (contiguous).
    const _Float16* gsrc;
    _Float16* ldst;
    if      (wave == 0) { gsrc = zh + (size_t)mblk * (8 * CHUNK); ldst = Ah; }
    else if (wave == 1) { gsrc = zl + (size_t)mblk * (8 * CHUNK); ldst = Al; }
    else if (wave == 2) { gsrc = ch + (size_t)nstrip * (8 * CHUNK); ldst = Bh; }
    else                { gsrc = cl + (size_t)nstrip * (8 * CHUNK); ldst = Bl; }
    gsrc += lane * 8;   // 16 B per lane

    f32x4 acc[4][4];
    #pragma unroll
    for (int i = 0; i < 4; ++i)
        #pragma unroll
        for (int j = 0; j < 4; ++j) acc[i][j] = (f32x4){0.f, 0.f, 0.f, 0.f};

    for (int kc8 = 0; kc8 < 8; ++kc8) {
        __syncthreads();   // prior fragment reads done
        #pragma unroll
        for (int j = 0; j < 8; ++j)   // 8 x 1 KB contiguous
            gld_lds16(gsrc + kc8 * CHUNK + j * 512, ldst + j * 512);
        __syncthreads();   // drains vmcnt: DMA complete

        f16x8 fah[4], fal[4], fbh[4], fbl[4];
        #pragma unroll
        for (int t = 0; t < 4; ++t) {
            int aoff = (wy * 64 + t * 16 + lr) * KC + quad * 8;
            int boff = (wx * 64 + t * 16 + lr) * KC + quad * 8;
            fah[t] = *(const f16x8*)&Ah[aoff];
            fal[t] = *(const f16x8*)&Al[aoff];
            fbh[t] = *(const f16x8*)&Bh[boff];
            fbl[t] = *(const f16x8*)&Bl[boff];
        }
        #pragma unroll
        for (int mt = 0; mt < 4; ++mt)
            #pragma unroll
            for (int nt = 0; nt < 4; ++nt) {
                acc[mt][nt] = __builtin_amdgcn_mfma_f32_16x16x32_f16(
                                  fah[mt], fbh[nt], acc[mt][nt], 0, 0, 0);
                acc[mt][nt] = __builtin_amdgcn_mfma_f32_16x16x32_f16(
                                  fal[mt], fbh[nt], acc[mt][nt], 0, 0, 0);
                acc[mt][nt] = __builtin_amdgcn_mfma_f32_16x16x32_f16(
                                  fah[mt], fbl[nt], acc[mt][nt], 0, 0, 0);
            }
    }

    // ---- Epilogue: score + argmin (D layout: col=lane&15, row=quad*4+reg) ----
    float cs[4];
    #pragma unroll
    for (int nt = 0; nt < 4; ++nt) cs[nt] = csq[n0 + wx * 64 + nt * 16 + lr];

    __syncthreads();
    float* cv = (float*)Ah;               // [128][2] vals
    int*   ci = (int*)Bh;                 // [128][2] idxs

    #pragma unroll
    for (int mt = 0; mt < 4; ++mt)
        #pragma unroll
        for (int r = 0; r < 4; ++r) {
            float bv = INFINITY; int bi = 0x7fffffff;
            #pragma unroll
            for (int nt = 0; nt < 4; ++nt) {
                float v = cs[nt] - 2.0f * acc[mt][nt][r];
                int   n = n0 + wx * 64 + nt * 16 + lr;
                if (v < bv || (v == bv && n < bi)) { bv = v; bi = n; }
            }
            #pragma unroll
            for (int msk = 1; msk < 16; msk <<= 1) {
                float ov = __shfl_xor(bv, msk, 64);
                int   oi = __shfl_xor(bi, msk, 64);
                if (ov < bv || (ov == bv && oi < bi)) { bv = ov; bi = oi; }
            }
            if (lr == 0) {
                int ml = wy * 64 + mt * 16 + quad * 4 + r;   // 0..127
                cv[ml * 2 + wx] = bv;
                ci[ml * 2 + wx] = bi;
            }
        }
    __syncthreads();

    if (tid < TM) {
        float v0 = cv[tid * 2], v1 = cv[tid * 2 + 1];
        int   i0 = ci[tid * 2], i1 = ci[tid * 2 + 1];
        bool take1 = (v1 < v0) || (v1 == v0 && i1 < i0);
        int token = mblk * TM + tid;
        pq[(size_t)token * NTILES + nstrip] =
            make_float2(take1 ? v1 : v0, __int_as_float(take1 ? i1 : i0));
    }
}

// ---------------------------------------------------------------------------
// Finalize: reduce 8 partials/token (contiguous 64 B), write index + gather z_q.
// 16 tokens per block.
// ---------------------------------------------------------------------------
__global__ __launch_bounds__(256) void vq_finalize(
        const float2* __restrict__ pq, const float* __restrict__ cb,
        float* __restrict__ zq, float* __restrict__ io) {
    __shared__ int best[16];
    const int tid = threadIdx.x;
    const int t0 = blockIdx.x * 16;

    if (tid < 16) {
        int token = t0 + tid;
        float bv = INFINITY; int bi = 0x7fffffff;
        #pragma unroll
        for (int j = 0; j < NTILES; ++j) {
            float2 p = pq[(size_t)token * NTILES + j];
            int i = __float_as_int(p.y);
            if (p.x < bv || (p.x == bv && i < bi)) { bv = p.x; bi = i; }
        }
        best[tid] = bi;
        io[token] = (float)bi;
    }
    __syncthreads();

    const int tr = tid >> 4, tc = tid & 15;
    const float* src = cb + (size_t)best[tr] * NDIM;
    float*       dst = zq + (size_t)(t0 + tr) * NDIM;
    #pragma unroll
    for (int q = 0; q < 4; ++q) {
        int col = q * 64 + tc * 4;
        *(float4*)&dst[col] = *(const float4*)&src[col];
    }
}

// ---------------------------------------------------------------------------
extern "C" void kernel_launch(void* const* d_in, const int* in_sizes, int n_in,
                              void* d_out, int out_size, void* d_ws, size_t ws_size,
                              hipStream_t stream) {
    const float* z  = (const float*)d_in[0];
    const float* cb = (const float*)d_in[1];

    float* zq = (float*)d_out;                        // 32768*256 floats
    float* io = (float*)d_out + (size_t)NTOK * NDIM;  // 32768 floats (indices)

    // z hi/lo blocked planes live in the zq region (exactly its 33.55 MB);
    // the GEMM consumes them before vq_finalize overwrites with final zq.
    _Float16* zh = (_Float16*)d_out;                  // 16.78 MB
    _Float16* zl = zh + (size_t)NTOK * NDIM;          // 16.78 MB

    _Float16* ch  = (_Float16*)d_ws;                  // 0.5 MB
    _Float16* cl  = ch + (size_t)NCODE * NDIM;        // 0.5 MB
    float*    csq = (float*)(cl + (size_t)NCODE * NDIM);  // 4 KB
    float2*   pq  = (float2*)(csq + NCODE);           // 2 MB
    // ws use ~3.1 MB

    prep_split<<<4096 + 128, 256, 0, stream>>>(z, cb, zh, zl, ch, cl, csq);

    dim3 grid(NTILES, NTOK / TM);                     // n-strip fastest
    vq_mfma_argmin<<<grid, 256, 0, stream>>>(zh, zl, ch, cl, csq, pq);

    vq_finalize<<<NTOK / 16, 256, 0, stream>>>(pq, cb, zq, io);
}

// Round 6
// 155.376 us; speedup vs baseline: 2.6108x; 1.0177x over previous
//
#include <hip/hip_runtime.h>
#include <math.h>

// Problem constants (B=8, T=4096, D=256, K=1024)
#define NTOK   32768
#define NDIM   256
#define NCODE  1024

#define TM 128
#define TN 128
#define KC 32
#define NTILES (NCODE / TN)   // 8
#define CHUNK  (128 * KC)     // 4096 f16 = 8 KB: one (row-block, kc8) plane chunk

typedef _Float16 f16x8 __attribute__((ext_vector_type(8)));
typedef float    f32x4 __attribute__((ext_vector_type(4)));

// async global->LDS DMA, 16 B per lane; LDS dst is wave-uniform base + lane*16
__device__ __forceinline__ void gld_lds16(const void* g, void* l) {
    __builtin_amdgcn_global_load_lds(
        (const __attribute__((address_space(1))) void*)g,
        (__attribute__((address_space(3))) void*)l, 16, 0, 0);
}

// ---------------------------------------------------------------------------
// Prep: split z and cb (fp32) into f16 hi/lo planes in BLOCKED k-major layout
//   plane[(rowblk*8 + kc8)*4096 + r*32 + k]  (rowblk=row/128, r=row%128)
// via an LDS transpose: reads coalesced, writes dense 16 B/lane in 512 B
// contiguous segments. Block = 64 rows, 8 row-groups of 8.
// Blocks [0,512): z.  Blocks [512,528): cb (+ exact fp32 csq).
// ---------------------------------------------------------------------------
#define SLDS 264   // LDS row stride (f16) for the 8x256 staging tile
__global__ __launch_bounds__(256) void prep_split(
        const float* __restrict__ z, const float* __restrict__ cb,
        _Float16* __restrict__ zh, _Float16* __restrict__ zl,
        _Float16* __restrict__ ch, _Float16* __restrict__ cl,
        float* __restrict__ csq) {
    __shared__ _Float16 Hs[8 * SLDS];   // 4.1 KB each
    __shared__ _Float16 Ls[8 * SLDS];

    const bool is_cb = blockIdx.x >= 512;
    const int  blk   = is_cb ? (blockIdx.x - 512) : blockIdx.x;
    const int  row0  = blk * 64;                 // first row of this block
    const float* src = (is_cb ? cb : z) + (size_t)row0 * NDIM;
    _Float16* ph = is_cb ? ch : zh;
    _Float16* pl = is_cb ? cl : zl;
    const int t = threadIdx.x;

    for (int grp = 0; grp < 8; ++grp) {          // 8 rows per group
        // ---- read + convert (coalesced fp32 reads) ----
        const int r = t >> 5;                    // 0..7 local row
        const int g = t & 31;                    // 8-col group within 256
        const float* p = src + ((size_t)(grp * 8 + r) * NDIM + g * 8);
        float4 a0 = *(const float4*)p;
        float4 a1 = *(const float4*)(p + 4);
        float v[8] = {a0.x, a0.y, a0.z, a0.w, a1.x, a1.y, a1.z, a1.w};
        f16x8 hi, lo;
        float s = 0.f;
        #pragma unroll
        for (int e = 0; e < 8; ++e) {
            _Float16 h = (_Float16)v[e];
            hi[e] = h;
            lo[e] = (_Float16)(v[e] - (float)h);
            s += v[e] * v[e];
        }
        if (grp) __syncthreads();                // prior group's LDS reads done
        *(f16x8*)&Hs[r * SLDS + g * 8] = hi;
        *(f16x8*)&Ls[r * SLDS + g * 8] = lo;
        if (is_cb) {                             // 32 consecutive lanes = one row
            #pragma unroll
            for (int off = 16; off > 0; off >>= 1) s += __shfl_down(s, off, 32);
            if ((t & 31) == 0) csq[row0 + grp * 8 + r] = s;
        }
        __syncthreads();

        // ---- write out: 8 kc8 x 2 planes x 512 B pieces, 16 B per thread x2 ----
        const int rowbase = row0 + grp * 8;      // global first row of group
        const int rb = rowbase >> 7;             // 128-row block index
        const int rr0 = rowbase & 127;           // offset within 128-row block
        #pragma unroll
        for (int io2 = 0; io2 < 2; ++io2) {
            int t2   = t + io2 * 256;            // 0..511
            int kc8  = t2 >> 6;                  // 0..7
            int pls  = (t2 >> 5) & 1;            // 0=hi 1=lo
            int slot = t2 & 31;                  // 16 B unit within 512 B piece
            int r2   = slot >> 2;                // 0..7 row
            int q    = slot & 3;                 // 16 B quarter of 64 B row piece
            const _Float16* S = pls ? Ls : Hs;
            f16x8 w = *(const f16x8*)&S[r2 * SLDS + kc8 * 32 + q * 8];
            _Float16* D = pls ? pl : ph;
            size_t dst = (size_t)(rb * 8 + kc8) * CHUNK + (rr0 + r2) * KC + q * 8;
            *(f16x8*)&D[dst] = w;
        }
    }
}

// ---------------------------------------------------------------------------
// Kernel G: f16-split MFMA GEMM (cross = z . cb) + fused per-strip argmin.
//   cross ~= ah.bh + al.bh + ah.bl ; score = csq[n] - 2*cross.
// Block: 128x128, 256 threads = 4 waves in 2x2; MFMA 16x16x32 f16.
// XCD-aware id swizzle: XCD x owns mblks {8k+x} for all strips, so each z
// chunk is fetched by exactly one XCD L2 (per-XCD set ~5 MB, L2-resident).
// ---------------------------------------------------------------------------
__global__ __launch_bounds__(256, 4) void vq_mfma_argmin(
        const _Float16* __restrict__ zh, const _Float16* __restrict__ zl,
        const _Float16* __restrict__ ch, const _Float16* __restrict__ cl,
        const float* __restrict__ csq,
        float2* __restrict__ pq) {
    __shared__ _Float16 Ah[TM * KC];   // 8 KB each, 32 KB total
    __shared__ _Float16 Al[TM * KC];
    __shared__ _Float16 Bh[TN * KC];
    __shared__ _Float16 Bl[TN * KC];

    const int tid = threadIdx.x;
    const int lin = blockIdx.x;
    const int x      = lin & 7;               // XCD slot (dispatch round-robin)
    const int j      = lin >> 3;
    const int nstrip = j & 7;
    const int mblk   = ((j >> 3) << 3) | x;   // XCD-local m-blocks
    const int n0     = nstrip * TN;
    const int wave   = tid >> 6;
    const int lane   = tid & 63;
    const int wy = wave >> 1, wx = wave & 1;  // 2x2 wave grid, 64x64 wave tiles
    const int quad = lane >> 4, lr = lane & 15;

    // Each wave stages one plane: blocked chunk base + lane*16B (contiguous).
    const _Float16* gsrc;
    _Float16* ldst;
    if      (wave == 0) { gsrc = zh + (size_t)mblk * (8 * CHUNK); ldst = Ah; }
    else if (wave == 1) { gsrc = zl + (size_t)mblk * (8 * CHUNK); ldst = Al; }
    else if (wave == 2) { gsrc = ch + (size_t)nstrip * (8 * CHUNK); ldst = Bh; }
    else                { gsrc = cl + (size_t)nstrip * (8 * CHUNK); ldst = Bl; }
    gsrc += lane * 8;   // 16 B per lane

    f32x4 acc[4][4];
    #pragma unroll
    for (int i = 0; i < 4; ++i)
        #pragma unroll
        for (int j2 = 0; j2 < 4; ++j2) acc[i][j2] = (f32x4){0.f, 0.f, 0.f, 0.f};

    for (int kc8 = 0; kc8 < 8; ++kc8) {
        __syncthreads();   // prior fragment reads done
        #pragma unroll
        for (int j2 = 0; j2 < 8; ++j2)   // 8 x 1 KB contiguous DMA
            gld_lds16(gsrc + kc8 * CHUNK + j2 * 512, ldst + j2 * 512);
        __syncthreads();   // drains vmcnt: DMA complete

        f16x8 fah[4], fal[4], fbh[4], fbl[4];
        #pragma unroll
        for (int t = 0; t < 4; ++t) {
            int aoff = (wy * 64 + t * 16 + lr) * KC + quad * 8;
            int boff = (wx * 64 + t * 16 + lr) * KC + quad * 8;
            fah[t] = *(const f16x8*)&Ah[aoff];
            fal[t] = *(const f16x8*)&Al[aoff];
            fbh[t] = *(const f16x8*)&Bh[boff];
            fbl[t] = *(const f16x8*)&Bl[boff];
        }
        #pragma unroll
        for (int mt = 0; mt < 4; ++mt)
            #pragma unroll
            for (int nt = 0; nt < 4; ++nt) {
                acc[mt][nt] = __builtin_amdgcn_mfma_f32_16x16x32_f16(
                                  fah[mt], fbh[nt], acc[mt][nt], 0, 0, 0);
                acc[mt][nt] = __builtin_amdgcn_mfma_f32_16x16x32_f16(
                                  fal[mt], fbh[nt], acc[mt][nt], 0, 0, 0);
                acc[mt][nt] = __builtin_amdgcn_mfma_f32_16x16x32_f16(
                                  fah[mt], fbl[nt], acc[mt][nt], 0, 0, 0);
            }
    }

    // ---- Epilogue: score + argmin (D layout: col=lane&15, row=quad*4+reg) ----
    float cs[4];
    #pragma unroll
    for (int nt = 0; nt < 4; ++nt) cs[nt] = csq[n0 + wx * 64 + nt * 16 + lr];

    __syncthreads();
    float* cv = (float*)Ah;               // [128][2] vals
    int*   ci = (int*)Bh;                 // [128][2] idxs

    #pragma unroll
    for (int mt = 0; mt < 4; ++mt)
        #pragma unroll
        for (int r = 0; r < 4; ++r) {
            float bv = INFINITY; int bi = 0x7fffffff;
            #pragma unroll
            for (int nt = 0; nt < 4; ++nt) {
                float v = cs[nt] - 2.0f * acc[mt][nt][r];
                int   n = n0 + wx * 64 + nt * 16 + lr;
                if (v < bv || (v == bv && n < bi)) { bv = v; bi = n; }
            }
            #pragma unroll
            for (int msk = 1; msk < 16; msk <<= 1) {
                float ov = __shfl_xor(bv, msk, 64);
                int   oi = __shfl_xor(bi, msk, 64);
                if (ov < bv || (ov == bv && oi < bi)) { bv = ov; bi = oi; }
            }
            if (lr == 0) {
                int ml = wy * 64 + mt * 16 + quad * 4 + r;   // 0..127
                cv[ml * 2 + wx] = bv;
                ci[ml * 2 + wx] = bi;
            }
        }
    __syncthreads();

    if (tid < TM) {
        float v0 = cv[tid * 2], v1 = cv[tid * 2 + 1];
        int   i0 = ci[tid * 2], i1 = ci[tid * 2 + 1];
        bool take1 = (v1 < v0) || (v1 == v0 && i1 < i0);
        int token = mblk * TM + tid;
        pq[(size_t)token * NTILES + nstrip] =
            make_float2(take1 ? v1 : v0, __int_as_float(take1 ? i1 : i0));
    }
}

// ---------------------------------------------------------------------------
// Finalize: reduce 8 partials/token (contiguous 64 B), write index + gather z_q.
// 16 tokens per block.
// ---------------------------------------------------------------------------
__global__ __launch_bounds__(256) void vq_finalize(
        const float2* __restrict__ pq, const float* __restrict__ cb,
        float* __restrict__ zq, float* __restrict__ io) {
    __shared__ int best[16];
    const int tid = threadIdx.x;
    const int t0 = blockIdx.x * 16;

    if (tid < 16) {
        int token = t0 + tid;
        float bv = INFINITY; int bi = 0x7fffffff;
        #pragma unroll
        for (int j = 0; j < NTILES; ++j) {
            float2 p = pq[(size_t)token * NTILES + j];
            int i = __float_as_int(p.y);
            if (p.x < bv || (p.x == bv && i < bi)) { bv = p.x; bi = i; }
        }
        best[tid] = bi;
        io[token] = (float)bi;
    }
    __syncthreads();

    const int tr = tid >> 4, tc = tid & 15;
    const float* src = cb + (size_t)best[tr] * NDIM;
    float*       dst = zq + (size_t)(t0 + tr) * NDIM;
    #pragma unroll
    for (int q = 0; q < 4; ++q) {
        int col = q * 64 + tc * 4;
        *(float4*)&dst[col] = *(const float4*)&src[col];
    }
}

// ---------------------------------------------------------------------------
extern "C" void kernel_launch(void* const* d_in, const int* in_sizes, int n_in,
                              void* d_out, int out_size, void* d_ws, size_t ws_size,
                              hipStream_t stream) {
    const float* z  = (const float*)d_in[0];
    const float* cb = (const float*)d_in[1];

    float* zq = (float*)d_out;                        // 32768*256 floats
    float* io = (float*)d_out + (size_t)NTOK * NDIM;  // 32768 floats (indices)

    // z hi/lo blocked planes live in the zq region (exactly its 33.55 MB);
    // the GEMM consumes them before vq_finalize overwrites with final zq.
    _Float16* zh = (_Float16*)d_out;                  // 16.78 MB
    _Float16* zl = zh + (size_t)NTOK * NDIM;          // 16.78 MB

    _Float16* ch  = (_Float16*)d_ws;                  // 0.5 MB
    _Float16* cl  = ch + (size_t)NCODE * NDIM;        // 0.5 MB
    float*    csq = (float*)(cl + (size_t)NCODE * NDIM);  // 4 KB
    float2*   pq  = (float2*)(csq + NCODE);           // 2 MB
    // ws use ~3.1 MB

    prep_split<<<512 + 16, 256, 0, stream>>>(z, cb, zh, zl, ch, cl, csq);

    vq_mfma_argmin<<<NTILES * (NTOK / TM), 256, 0, stream>>>(
        zh, zl, ch, cl, csq, pq);

    vq_finalize<<<NTOK / 16, 256, 0, stream>>>(pq, cb, zq, io);
}

// Round 7
// 139.724 us; speedup vs baseline: 2.9033x; 1.1120x over previous
//
#include <hip/hip_runtime.h>
#include <math.h>

// Problem constants (B=8, T=4096, D=256, K=1024)
#define NTOK   32768
#define NDIM   256
#define NCODE  1024
#define NSTRIP 8              // 8 strips x 128 codes
#define CHUNK  (128 * 32)     // 4096 f16 = 8 KB: one (code-strip, kc8) plane chunk

typedef _Float16 f16x8 __attribute__((ext_vector_type(8)));
typedef float    f32x4 __attribute__((ext_vector_type(4)));

// async global->LDS DMA, 16 B per lane; LDS dst is wave-uniform base + lane*16
__device__ __forceinline__ void gld_lds16(const void* g, void* l) {
    __builtin_amdgcn_global_load_lds(
        (const __attribute__((address_space(1))) void*)g,
        (__attribute__((address_space(3))) void*)l, 16, 0, 0);
}

// ---------------------------------------------------------------------------
// Prep: split codebook (fp32) into f16 hi/lo planes in blocked k-major layout
//   plane[(strip*8 + kc8)*4096 + r*32 + k]   (strip=row/128, r=row%128)
// plus exact fp32 row norms. 1 MB total -- small scattered writes are fine.
// ---------------------------------------------------------------------------
__global__ __launch_bounds__(256) void prep_cb(
        const float* __restrict__ cb,
        _Float16* __restrict__ ch, _Float16* __restrict__ cl,
        float* __restrict__ csq) {
    const int L   = blockIdx.x * 256 + threadIdx.x;   // 0..32767
    const int row = L >> 5;                           // code 0..1023
    const int g   = L & 31;                           // 8-elem group in 256 dims

    const float* src = cb + (size_t)row * NDIM + g * 8;
    float4 a0 = *(const float4*)src;
    float4 a1 = *(const float4*)(src + 4);
    float v[8] = {a0.x, a0.y, a0.z, a0.w, a1.x, a1.y, a1.z, a1.w};
    f16x8 hi, lo;
    float s = 0.f;
    #pragma unroll
    for (int e = 0; e < 8; ++e) {
        _Float16 h = (_Float16)v[e];
        hi[e] = h;
        lo[e] = (_Float16)(v[e] - (float)h);
        s += v[e] * v[e];
    }
    const size_t dst = (size_t)((row >> 7) * 8 + (g >> 2)) * CHUNK
                     + (row & 127) * 32 + (g & 3) * 8;
    *(f16x8*)&ch[dst] = hi;
    *(f16x8*)&cl[dst] = lo;
    // 32 consecutive threads cover one row
    #pragma unroll
    for (int off = 16; off > 0; off >>= 1) s += __shfl_down(s, off, 32);
    if ((threadIdx.x & 31) == 0) csq[row] = s;
}

// ---------------------------------------------------------------------------
// Main: A-stationary fused VQ.
// Block = 64 tokens, 4 waves; wave w owns m-tile rows m0+w*16..+15.
// A (z) hi/lo fragments live in REGISTERS for the full K=256 (loaded once).
// Loop: 8 strips x 2 K-halves; stage cb planes (32 KB) into LDS via DMA;
// 3-pass f16 MFMA (ah.bh + al.bh + ah.bl); per-lane running argmin; final
// butterfly + index write + zq gather all in-block. No partials, no finalize.
// Layouts (verified): A/B frag [row=lane&15][k=(lane>>4)*8+j]; D col=lane&15,
// row=(lane>>4)*4+reg.
// ---------------------------------------------------------------------------
__global__ __launch_bounds__(256, 2) void vq_main(
        const float* __restrict__ z,
        const _Float16* __restrict__ ch, const _Float16* __restrict__ cl,
        const float* __restrict__ csq, const float* __restrict__ cb,
        float* __restrict__ zq, float* __restrict__ io) {
    __shared__ _Float16 Bh[4 * CHUNK];   // 32 KB (4 kc8 chunks of current half)
    __shared__ _Float16 Bl[4 * CHUNK];   // 32 KB

    const int tid  = threadIdx.x;
    const int w    = tid >> 6;
    const int lane = tid & 63;
    const int quad = lane >> 4, lr = lane & 15;
    const int m0   = blockIdx.x * 64;

    // ---- Phase 0: load my z rows, split into hi/lo register fragments ----
    // A-frag for kc8: A[m=lr][k=kc8*32 + quad*8 + j]
    f16x8 ah[8], al[8];
    {
        const float* zp = z + (size_t)(m0 + w * 16 + lr) * NDIM + quad * 8;
        #pragma unroll
        for (int c = 0; c < 8; ++c) {
            float4 a0 = *(const float4*)(zp + c * 32);
            float4 a1 = *(const float4*)(zp + c * 32 + 4);
            float v[8] = {a0.x, a0.y, a0.z, a0.w, a1.x, a1.y, a1.z, a1.w};
            #pragma unroll
            for (int e = 0; e < 8; ++e) {
                _Float16 h = (_Float16)v[e];
                ah[c][e] = h;
                al[c][e] = (_Float16)(v[e] - (float)h);
            }
        }
    }

    float bv[4];
    int   bi[4];
    #pragma unroll
    for (int r = 0; r < 4; ++r) { bv[r] = INFINITY; bi[r] = 0x7fffffff; }

    f32x4 acc[8];
    #pragma unroll
    for (int nt = 0; nt < 8; ++nt) acc[nt] = (f32x4){0.f, 0.f, 0.f, 0.f};

    for (int strip = 0; strip < NSTRIP; ++strip) {
        // csq for my 8 columns of this strip (L2-hot; hidden under DMA/MFMA)
        float cs[8];
        #pragma unroll
        for (int nt = 0; nt < 8; ++nt)
            cs[nt] = csq[strip * 128 + nt * 16 + lr];

        #pragma unroll
        for (int kh = 0; kh < 2; ++kh) {
            __syncthreads();   // all waves done reading previous LDS contents
            // Stage 4 kc8 chunks (hi+lo) of this strip-half: wave w covers
            // its quarter (one chunk) with 8 x 1 KB contiguous DMAs per plane.
            {
                const size_t base = (size_t)(strip * 8 + kh * 4) * CHUNK
                                  + w * CHUNK + lane * 8;
                const _Float16* sh = ch + base;
                const _Float16* sl = cl + base;
                #pragma unroll
                for (int i = 0; i < 8; ++i) {
                    gld_lds16(sh + i * 512, Bh + w * CHUNK + i * 512);
                    gld_lds16(sl + i * 512, Bl + w * CHUNK + i * 512);
                }
            }
            __syncthreads();   // drain: DMA complete

            #pragma unroll
            for (int k4 = 0; k4 < 4; ++k4) {
                const int kg = kh * 4 + k4;       // global kc8 index
                f16x8 fbh[8], fbl[8];
                #pragma unroll
                for (int nt = 0; nt < 8; ++nt) {
                    const int off = k4 * CHUNK + (nt * 16 + lr) * 32 + quad * 8;
                    fbh[nt] = *(const f16x8*)&Bh[off];
                    fbl[nt] = *(const f16x8*)&Bl[off];
                }
                #pragma unroll
                for (int nt = 0; nt < 8; ++nt) {
                    acc[nt] = __builtin_amdgcn_mfma_f32_16x16x32_f16(
                                  ah[kg], fbh[nt], acc[nt], 0, 0, 0);
                    acc[nt] = __builtin_amdgcn_mfma_f32_16x16x32_f16(
                                  al[kg], fbh[nt], acc[nt], 0, 0, 0);
                    acc[nt] = __builtin_amdgcn_mfma_f32_16x16x32_f16(
                                  ah[kg], fbl[nt], acc[nt], 0, 0, 0);
                }
            }
        }

        // ---- fold this strip into the running per-lane argmin ----
        #pragma unroll
        for (int r = 0; r < 4; ++r)
            #pragma unroll
            for (int nt = 0; nt < 8; ++nt) {
                float v = cs[nt] - 2.0f * acc[nt][r];
                int   n = strip * 128 + nt * 16 + lr;
                if (v < bv[r] || (v == bv[r] && n < bi[r])) { bv[r] = v; bi[r] = n; }
            }
        #pragma unroll
        for (int nt = 0; nt < 8; ++nt) acc[nt] = (f32x4){0.f, 0.f, 0.f, 0.f};
    }

    // ---- final reduction: butterfly over the 16 lanes sharing each row ----
    #pragma unroll
    for (int msk = 1; msk < 16; msk <<= 1)
        #pragma unroll
        for (int r = 0; r < 4; ++r) {
            float ov = __shfl_xor(bv[r], msk, 64);
            int   oi = __shfl_xor(bi[r], msk, 64);
            if (ov < bv[r] || (ov == bv[r] && oi < bi[r])) { bv[r] = ov; bi[r] = oi; }
        }

    __syncthreads();                  // done with Bh/Bl; reuse as scratch
    int* bestS = (int*)Bh;            // [64] final indices
    if (lr == 0) {
        #pragma unroll
        for (int r = 0; r < 4; ++r) {
            int row = w * 16 + quad * 4 + r;
            bestS[row] = bi[r];
            io[m0 + row] = (float)bi[r];
        }
    }
    __syncthreads();

    // ---- gather z_q: 64 rows x 1 KB from cb (L2-hot), coalesced float4 ----
    const int tr = tid >> 4, tc = tid & 15;
    #pragma unroll
    for (int p = 0; p < 4; ++p) {
        int row = p * 16 + tr;
        const float* src = cb + (size_t)bestS[row] * NDIM;
        float*       dst = zq + (size_t)(m0 + row) * NDIM;
        #pragma unroll
        for (int q = 0; q < 4; ++q) {
            int col = q * 64 + tc * 4;
            *(float4*)&dst[col] = *(const float4*)&src[col];
        }
    }
}

// ---------------------------------------------------------------------------
extern "C" void kernel_launch(void* const* d_in, const int* in_sizes, int n_in,
                              void* d_out, int out_size, void* d_ws, size_t ws_size,
                              hipStream_t stream) {
    const float* z  = (const float*)d_in[0];
    const float* cb = (const float*)d_in[1];

    float* zq = (float*)d_out;                        // 32768*256 floats
    float* io = (float*)d_out + (size_t)NTOK * NDIM;  // 32768 floats (indices)

    _Float16* ch  = (_Float16*)d_ws;                  // 0.5 MB
    _Float16* cl  = ch + (size_t)NCODE * NDIM;        // 0.5 MB
    float*    csq = (float*)(cl + (size_t)NCODE * NDIM);  // 4 KB
    // ws use ~1 MB

    prep_cb<<<NCODE * 32 / 256, 256, 0, stream>>>(cb, ch, cl, csq);

    vq_main<<<NTOK / 64, 256, 0, stream>>>(z, ch, cl, csq, cb, zq, io);
}

// Round 8
// 132.978 us; speedup vs baseline: 3.0506x; 1.0507x over previous
//
#include <hip/hip_runtime.h>
#include <math.h>

// Problem constants (B=8, T=4096, D=256, K=1024)
#define NTOK   32768
#define NDIM   256
#define NCODE  1024
#define NSTRIP 8              // 8 strips x 128 codes
#define CHUNK  (128 * 32)     // 4096 f16 = 8 KB: one (code-strip, kc8) plane chunk

typedef _Float16 f16x8 __attribute__((ext_vector_type(8)));
typedef float    f32x4 __attribute__((ext_vector_type(4)));

// async global->LDS DMA, 16 B per lane; LDS dst is wave-uniform base + lane*16
__device__ __forceinline__ void gld_lds16(const void* g, void* l) {
    __builtin_amdgcn_global_load_lds(
        (const __attribute__((address_space(1))) void*)g,
        (__attribute__((address_space(3))) void*)l, 16, 0, 0);
}

// ---------------------------------------------------------------------------
// Prep: split codebook (fp32) into f16 hi/lo planes in blocked k-major layout
//   plane[(strip*8 + kc8)*4096 + r*32 + k]   (strip=row/128, r=row%128)
// plus exact fp32 row norms. 1 MB total.
// ---------------------------------------------------------------------------
__global__ __launch_bounds__(256) void prep_cb(
        const float* __restrict__ cb,
        _Float16* __restrict__ ch, _Float16* __restrict__ cl,
        float* __restrict__ csq) {
    const int L   = blockIdx.x * 256 + threadIdx.x;   // 0..32767
    const int row = L >> 5;                           // code 0..1023
    const int g   = L & 31;                           // 8-elem group in 256 dims

    const float* src = cb + (size_t)row * NDIM + g * 8;
    float4 a0 = *(const float4*)src;
    float4 a1 = *(const float4*)(src + 4);
    float v[8] = {a0.x, a0.y, a0.z, a0.w, a1.x, a1.y, a1.z, a1.w};
    f16x8 hi, lo;
    float s = 0.f;
    #pragma unroll
    for (int e = 0; e < 8; ++e) {
        _Float16 h = (_Float16)v[e];
        hi[e] = h;
        lo[e] = (_Float16)(v[e] - (float)h);
        s += v[e] * v[e];
    }
    const size_t dst = (size_t)((row >> 7) * 8 + (g >> 2)) * CHUNK
                     + (row & 127) * 32 + (g & 3) * 8;
    *(f16x8*)&ch[dst] = hi;
    *(f16x8*)&cl[dst] = lo;
    #pragma unroll
    for (int off = 16; off > 0; off >>= 1) s += __shfl_down(s, off, 32);
    if ((threadIdx.x & 31) == 0) csq[row] = s;
}

// ---------------------------------------------------------------------------
// Main: A-stationary fused VQ with 2x2 wave partition.
// Block = 64 tokens, 4 waves. Wave w = (my=w>>1, nx=w&1): owns token rows
// [my*32, my*32+32) (A hi/lo register-resident for full K=256) and code
// columns nx-half of every strip (4 of 8 n-tiles) -> each B element is read
// by only 2 waves (halves LDS pipe load vs all-wave reads).
// 3-pass f16 MFMA (ah.bh + al.bh + ah.bl); per-lane running argmin per strip;
// butterfly + cross-nx LDS merge + index write + zq gather in-block.
// Layouts (verified): A/B frag [row=lane&15][k=(lane>>4)*8+j]; D col=lane&15,
// row=(lane>>4)*4+reg.
// ---------------------------------------------------------------------------
__global__ __launch_bounds__(256, 2) void vq_main(
        const float* __restrict__ z,
        const _Float16* __restrict__ ch, const _Float16* __restrict__ cl,
        const float* __restrict__ csq, const float* __restrict__ cb,
        float* __restrict__ zq, float* __restrict__ io) {
    __shared__ _Float16 Bh[4 * CHUNK];   // 32 KB (4 kc8 chunks of current half)
    __shared__ _Float16 Bl[4 * CHUNK];   // 32 KB

    const int tid  = threadIdx.x;
    const int w    = tid >> 6;
    const int lane = tid & 63;
    const int quad = lane >> 4, lr = lane & 15;
    const int my   = w >> 1, nx = w & 1;
    const int m0   = blockIdx.x * 64;

    // ---- Phase 0: load my 2 m-tiles of z, split into hi/lo register frags ----
    // A-frag for (mt, kc8): A[m = my*32 + mt*16 + lr][k = kc8*32 + quad*8 + j]
    f16x8 ah[2][8], al[2][8];
    #pragma unroll
    for (int mt = 0; mt < 2; ++mt) {
        const float* zp = z + (size_t)(m0 + my * 32 + mt * 16 + lr) * NDIM
                        + quad * 8;
        #pragma unroll
        for (int c = 0; c < 8; ++c) {
            float4 a0 = *(const float4*)(zp + c * 32);
            float4 a1 = *(const float4*)(zp + c * 32 + 4);
            float v[8] = {a0.x, a0.y, a0.z, a0.w, a1.x, a1.y, a1.z, a1.w};
            #pragma unroll
            for (int e = 0; e < 8; ++e) {
                _Float16 h = (_Float16)v[e];
                ah[mt][c][e] = h;
                al[mt][c][e] = (_Float16)(v[e] - (float)h);
            }
        }
    }

    float bv[2][4];
    int   bi[2][4];
    #pragma unroll
    for (int mt = 0; mt < 2; ++mt)
        #pragma unroll
        for (int r = 0; r < 4; ++r) { bv[mt][r] = INFINITY; bi[mt][r] = 0x7fffffff; }

    f32x4 acc[2][4];
    #pragma unroll
    for (int mt = 0; mt < 2; ++mt)
        #pragma unroll
        for (int t = 0; t < 4; ++t) acc[mt][t] = (f32x4){0.f, 0.f, 0.f, 0.f};

    for (int strip = 0; strip < NSTRIP; ++strip) {
        // csq for my 4 column-tiles of this strip (L2-hot)
        float cs[4];
        #pragma unroll
        for (int t = 0; t < 4; ++t)
            cs[t] = csq[strip * 128 + (nx * 4 + t) * 16 + lr];

        #pragma unroll
        for (int kh = 0; kh < 2; ++kh) {
            __syncthreads();   // all waves done reading previous LDS contents
            // Stage this strip-half: wave w DMAs chunk k4=w (hi+lo), 8x1KB each.
            {
                const size_t base = (size_t)(strip * 8 + kh * 4 + w) * CHUNK
                                  + lane * 8;
                const _Float16* sh = ch + base;
                const _Float16* sl = cl + base;
                #pragma unroll
                for (int i = 0; i < 8; ++i) {
                    gld_lds16(sh + i * 512, Bh + w * CHUNK + i * 512);
                    gld_lds16(sl + i * 512, Bl + w * CHUNK + i * 512);
                }
            }
            __syncthreads();   // drain: DMA complete

            #pragma unroll
            for (int k4 = 0; k4 < 4; ++k4) {
                const int kg = kh * 4 + k4;       // global kc8 index
                f16x8 fbh[4], fbl[4];
                #pragma unroll
                for (int t = 0; t < 4; ++t) {
                    const int off = k4 * CHUNK
                                  + ((nx * 4 + t) * 16 + lr) * 32 + quad * 8;
                    fbh[t] = *(const f16x8*)&Bh[off];
                    fbl[t] = *(const f16x8*)&Bl[off];
                }
                #pragma unroll
                for (int mt = 0; mt < 2; ++mt)
                    #pragma unroll
                    for (int t = 0; t < 4; ++t) {
                        acc[mt][t] = __builtin_amdgcn_mfma_f32_16x16x32_f16(
                                         ah[mt][kg], fbh[t], acc[mt][t], 0, 0, 0);
                        acc[mt][t] = __builtin_amdgcn_mfma_f32_16x16x32_f16(
                                         al[mt][kg], fbh[t], acc[mt][t], 0, 0, 0);
                        acc[mt][t] = __builtin_amdgcn_mfma_f32_16x16x32_f16(
                                         ah[mt][kg], fbl[t], acc[mt][t], 0, 0, 0);
                    }
            }
        }

        // ---- fold this strip into the running per-lane argmin ----
        #pragma unroll
        for (int mt = 0; mt < 2; ++mt)
            #pragma unroll
            for (int r = 0; r < 4; ++r)
                #pragma unroll
                for (int t = 0; t < 4; ++t) {
                    float v = cs[t] - 2.0f * acc[mt][t][r];
                    int   n = strip * 128 + (nx * 4 + t) * 16 + lr;
                    if (v < bv[mt][r] || (v == bv[mt][r] && n < bi[mt][r])) {
                        bv[mt][r] = v; bi[mt][r] = n;
                    }
                }
        #pragma unroll
        for (int mt = 0; mt < 2; ++mt)
            #pragma unroll
            for (int t = 0; t < 4; ++t) acc[mt][t] = (f32x4){0.f, 0.f, 0.f, 0.f};
    }

    // ---- butterfly over the 16 lanes sharing each row ----
    #pragma unroll
    for (int msk = 1; msk < 16; msk <<= 1)
        #pragma unroll
        for (int mt = 0; mt < 2; ++mt)
            #pragma unroll
            for (int r = 0; r < 4; ++r) {
                float ov = __shfl_xor(bv[mt][r], msk, 64);
                int   oi = __shfl_xor(bi[mt][r], msk, 64);
                if (ov < bv[mt][r] || (ov == bv[mt][r] && oi < bi[mt][r])) {
                    bv[mt][r] = ov; bi[mt][r] = oi;
                }
            }

    __syncthreads();                         // done with Bh/Bl; reuse as scratch
    float* sval  = (float*)Bh;               // [64][2]
    int*   sidx  = (int*)&Bh[512];           // [64][2]
    int*   bestS = (int*)&Bh[1024];          // [64]

    if (lr == 0) {
        #pragma unroll
        for (int mt = 0; mt < 2; ++mt)
            #pragma unroll
            for (int r = 0; r < 4; ++r) {
                int row = my * 32 + mt * 16 + quad * 4 + r;   // 0..63
                sval[row * 2 + nx] = bv[mt][r];
                sidx[row * 2 + nx] = bi[mt][r];
            }
    }
    __syncthreads();

    if (tid < 64) {
        float v0 = sval[tid * 2], v1 = sval[tid * 2 + 1];
        int   i0 = sidx[tid * 2], i1 = sidx[tid * 2 + 1];
        bool take1 = (v1 < v0) || (v1 == v0 && i1 < i0);
        int best = take1 ? i1 : i0;
        bestS[tid] = best;
        io[m0 + tid] = (float)best;
    }
    __syncthreads();

    // ---- gather z_q: 64 rows x 1 KB from cb (L2-hot), coalesced float4 ----
    const int tr = tid >> 4, tc = tid & 15;
    #pragma unroll
    for (int p = 0; p < 4; ++p) {
        int row = p * 16 + tr;
        const float* src = cb + (size_t)bestS[row] * NDIM;
        float*       dst = zq + (size_t)(m0 + row) * NDIM;
        #pragma unroll
        for (int q = 0; q < 4; ++q) {
            int col = q * 64 + tc * 4;
            *(float4*)&dst[col] = *(const float4*)&src[col];
        }
    }
}

// ---------------------------------------------------------------------------
extern "C" void kernel_launch(void* const* d_in, const int* in_sizes, int n_in,
                              void* d_out, int out_size, void* d_ws, size_t ws_size,
                              hipStream_t stream) {
    const float* z  = (const float*)d_in[0];
    const float* cb = (const float*)d_in[1];

    float* zq = (float*)d_out;                        // 32768*256 floats
    float* io = (float*)d_out + (size_t)NTOK * NDIM;  // 32768 floats (indices)

    _Float16* ch  = (_Float16*)d_ws;                  // 0.5 MB
    _Float16* cl  = ch + (size_t)NCODE * NDIM;        // 0.5 MB
    float*    csq = (float*)(cl + (size_t)NCODE * NDIM);  // 4 KB
    // ws use ~1 MB

    prep_cb<<<NCODE * 32 / 256, 256, 0, stream>>>(cb, ch, cl, csq);

    vq_main<<<NTOK / 64, 256, 0, stream>>>(z, ch, cl, csq, cb, zq, io);
}